// Round 15
// baseline (563.158 us; speedup 1.0000x reference)
//
#include <hip/hip_runtime.h>
#include <cstdint>
#include <cstddef>

// ---------------------------------------------------------------------------
// AffineMultiQueryHardAttentionEncoder
//   scores[m] = max_n ( (q[n]*a) . k[m] ), top-64, softmax, sum w_i * V[idx_i]
// R15: producer-consumer scores_gemm (per-wave waitcnt independence).
//   - 4 producer waves: keys read in FULL 1KB page bursts (dwordx4 = 64
//     lanes x 16B contiguous), issued a half-superstep ahead; cvt -> ring-2
//     A-LDS. Never waits on B. Fixes the DRAM row-thrash that capped every
//     interleaved design (R1-R14) at <=2.7 TB/s.
//   - 4 consumer waves: B ring-2 glds (L2) + 32 MFMA/iter, per-iter
//     vmcnt(0)+lgkm(0)+s_barrier on their OWN counters (B-only stream).
//   - A rows padded 72B (+iter pad) ~2-way banks; B g-XOR both-sides (prep_q).
//   - tail (two-level hist + exact rescore + final): R12 verbatim.
// ---------------------------------------------------------------------------

typedef __attribute__((ext_vector_type(8))) short bf16x8;
typedef __attribute__((ext_vector_type(4))) float f32x4;

static constexpr int NQ = 512;
static constexpr int DD = 1024;
static constexpr int MK = 100000;
static constexpr int BM = 64;
static constexpr int MBLK = (MK + BM - 1) / BM;        // 1563
static constexpr int CAP = 1024;

// workspace layout (bytes)
static constexpr size_t QSTAGE_OFF   = 0;    // [32 T][512 q][4 g'][16B] = 1 MiB
static constexpr size_t QSTAGE_BYTES = (size_t)32 * NQ * 4 * 16;
static constexpr size_t SCORES_OFF   = QSTAGE_OFF + QSTAGE_BYTES;
static constexpr size_t SCORES_BYTES = (size_t)MBLK * BM * 4;
static constexpr size_t CIDX_OFF     = SCORES_OFF + SCORES_BYTES;
static constexpr size_t RESC_OFF     = CIDX_OFF + (size_t)CAP * 4;
static constexpr size_t CNT_OFF      = RESC_OFF + (size_t)CAP * 4;
static constexpr size_t HISTC_OFF    = CNT_OFF + 64;
static constexpr size_t HISTF_OFF    = HISTC_OFF + 8192 * 4;
static constexpr size_t TB_OFF       = HISTF_OFF + 8192 * 4;
static constexpr size_t VLO_OFF      = TB_OFF + 64;

// gemm LDS:
//   A ring-2: [2][8 it][64 rows][72B] + 32B pad/iter  -> 2*8*4640 = 74240 @0
//   B ring-2: [2][512 q][4 g'][16B] = 2*32768 = 65536 @74240
//   wmax [4][64] f32 @139776 ; total 140800
static constexpr int AIT  = 4640;              // 64*72 + 32
static constexpr int ARING = 8 * AIT;          // 37120
static constexpr int BOFF = 2 * ARING;         // 74240
static constexpr int WOFF = BOFF + 2 * 32768;  // 139776
static constexpr int GEMM_LDS = WOFF + 1024;   // 140800

static __device__ __forceinline__ unsigned short f32_to_bf16_rne(float f) {
    unsigned int u = __float_as_uint(f);
    unsigned int r = (u + 0x7FFFu + ((u >> 16) & 1u)) >> 16;
    return (unsigned short)r;
}
static __device__ __forceinline__ unsigned int xform(float f) {
    unsigned int u = __float_as_uint(f);
    return u ^ ((unsigned int)((int)u >> 31) | 0x80000000u);
}
static __device__ __forceinline__ float unxform(unsigned int u) {
    unsigned int b = (u & 0x80000000u) ? (u ^ 0x80000000u) : ~u;
    return __uint_as_float(b);
}

typedef __attribute__((address_space(1))) const unsigned int g1u32;
typedef __attribute__((address_space(3))) unsigned int l3u32;
static __device__ __forceinline__ void async16(const void* g, void* l) {
    __builtin_amdgcn_global_load_lds((g1u32*)g, (l3u32*)(uintptr_t)l, 16, 0, 0);
}

// ---------------------------------------------------------------------------
// prep_q: qa = q*a -> bf16 RNE. Image chunk (T,q,g') at byte
//   T*32768 + q*64 + g'*16  holds  qa[q][T*32 + ((g'^(q&3))*8) .. +7]
// (g-XOR applied on BOTH write and read sides - rule #21)
// ---------------------------------------------------------------------------
__global__ void prep_q(const float* __restrict__ q, const float* __restrict__ a,
                       unsigned short* __restrict__ qs) {
    int id = blockIdx.x * 256 + threadIdx.x;    // 0..65535
    int gp = id & 3;
    int qq = (id >> 2) & 511;
    int T  = id >> 11;
    int col = T * 32 + ((gp ^ (qq & 3)) << 3);

    const float* qrow = q + (size_t)qq * DD + col;
    float4 v0 = *(const float4*)(qrow);
    float4 v1 = *(const float4*)(qrow + 4);
    float4 a0 = *(const float4*)(a + col);
    float4 a1 = *(const float4*)(a + col + 4);
    float f[8] = {v0.x * a0.x, v0.y * a0.y, v0.z * a0.z, v0.w * a0.w,
                  v1.x * a1.x, v1.y * a1.y, v1.z * a1.z, v1.w * a1.w};
    bf16x8 o;
#pragma unroll
    for (int t = 0; t < 8; ++t) o[t] = (short)f32_to_bf16_rne(f[t]);
    *(bf16x8*)(qs + (size_t)id * 8) = o;
}

// ---------------------------------------------------------------------------
// producer-consumer prescreen GEMM + column max
// ---------------------------------------------------------------------------
__launch_bounds__(512)
__global__ void scores_gemm(const float* __restrict__ keys,
                            const unsigned short* __restrict__ qs,
                            float* __restrict__ scores) {
    extern __shared__ char smem[];
    const int tid  = threadIdx.x;
    const int wid  = tid >> 6;
    const int lane = tid & 63;
    const int g    = lane >> 4;
    const int r16  = lane & 15;
    const int gx   = g ^ (r16 & 3);            // B g-XOR (q&3 == r16&3)

    // bijective XCD swizzle (m204); nwg = 1563
    const int nwg = gridDim.x;
    const int qq8 = nwg >> 3, rr8 = nwg & 7;
    const int xcd = blockIdx.x & 7, loc = blockIdx.x >> 3;
    const int mb  = (xcd < rr8 ? xcd * (qq8 + 1) : rr8 * (qq8 + 1) + (xcd - rr8) * qq8) + loc;
    const int m0  = mb * BM;

    if (wid < 4) {
        // =================== CONSUMER (waves 0-3) ===================
        const int wq = wid;
        const char* qsB = (const char*)qs + wq * 8192 + (size_t)lane * 16;

        f32x4 acc[4][8] = {};

        // prologue: stage B(0) -> ring0
#pragma unroll
        for (int i = 0; i < 8; ++i)
            async16(qsB + i * 1024, smem + BOFF + wq * 8192 + i * 1024);
        asm volatile("s_waitcnt vmcnt(0)" ::: "memory");
        __builtin_amdgcn_s_barrier();
        __builtin_amdgcn_sched_barrier(0);

#pragma unroll
        for (int T = 0; T < 32; ++T) {
            if (T + 1 < 32) {
#pragma unroll
                for (int i = 0; i < 8; ++i)
                    async16(qsB + (size_t)(T + 1) * 32768 + i * 1024,
                            smem + BOFF + ((T + 1) & 1) * 32768 + wq * 8192 + i * 1024);
            }
            const int it = T & 7, sr = (T >> 3) & 1, br = T & 1;
            bf16x8 af[4], bfr[8];
#pragma unroll
            for (int rt = 0; rt < 4; ++rt)
                af[rt] = *(const bf16x8*)(smem + sr * ARING + it * AIT +
                                          (rt * 16 + r16) * 72 + g * 16);
#pragma unroll
            for (int ct = 0; ct < 8; ++ct)
                bfr[ct] = *(const bf16x8*)(smem + BOFF + br * 32768 +
                                           (wq * 128 + ct * 16 + r16) * 64 + gx * 16);
            __builtin_amdgcn_s_setprio(1);
#pragma unroll
            for (int rt = 0; rt < 4; ++rt)
#pragma unroll
                for (int ct = 0; ct < 8; ++ct)
                    acc[rt][ct] = __builtin_amdgcn_mfma_f32_16x16x32_bf16(
                        af[rt], bfr[ct], acc[rt][ct], 0, 0, 0);
            __builtin_amdgcn_s_setprio(0);
            asm volatile("s_waitcnt vmcnt(0) lgkmcnt(0)" ::: "memory");
            __builtin_amdgcn_s_barrier();
            __builtin_amdgcn_sched_barrier(0);
        }

        // epilogue: key = rt*16 + g*4 + r ; q = wq*128 + ct*16 + r16
        float* wmax = (float*)(smem + WOFF);   // [4 wq][64 keys]
#pragma unroll
        for (int rt = 0; rt < 4; ++rt) {
#pragma unroll
            for (int r = 0; r < 4; ++r) {
                float mx = acc[rt][0][r];
#pragma unroll
                for (int ct = 1; ct < 8; ++ct) mx = fmaxf(mx, acc[rt][ct][r]);
#pragma unroll
                for (int off = 1; off < 16; off <<= 1)
                    mx = fmaxf(mx, __shfl_xor(mx, off));
                if (r16 == 0) wmax[wq * 64 + rt * 16 + g * 4 + r] = mx;
            }
        }
        asm volatile("s_waitcnt lgkmcnt(0)" ::: "memory");
        __builtin_amdgcn_s_barrier();
        __builtin_amdgcn_sched_barrier(0);
        if (tid < BM) {
            float mx = fmaxf(fmaxf(wmax[tid], wmax[64 + tid]),
                             fmaxf(wmax[128 + tid], wmax[192 + tid]));
            int gm = m0 + tid;
            if (gm < MK) scores[gm] = mx;
        }
    } else {
        // =================== PRODUCER (waves 4-7) ===================
        const int pid = wid - 4;               // 0..3, owns rows pid*16..+16
        const float* prow[16];
#pragma unroll
        for (int j = 0; j < 16; ++j) {
            int rl = pid * 16 + j;
            int gr = m0 + rl; if (gr > MK - 1) gr = MK - 1;
            prow[j] = keys + (size_t)gr * DD + lane * 4;
        }
        // LDS write addr per lane: it=lane>>3, g=(lane&7)>>1, pos=(lane&1)*8
        int pwb[16];
#pragma unroll
        for (int j = 0; j < 16; ++j) {
            int rl = pid * 16 + j;
            pwb[j] = (lane >> 3) * AIT + rl * 72 + ((lane & 7) >> 1) * 16 + (lane & 1) * 8;
        }

        f32x4 Pr[16];

        // prologue: superstep 0 -> ring 0
#pragma unroll
        for (int j = 0; j < 16; ++j) Pr[j] = *(const f32x4*)(prow[j]);
#pragma unroll
        for (int j = 0; j < 16; ++j) {
            unsigned long long pk =
                (unsigned long long)f32_to_bf16_rne(Pr[j].x)
              | ((unsigned long long)f32_to_bf16_rne(Pr[j].y) << 16)
              | ((unsigned long long)f32_to_bf16_rne(Pr[j].z) << 32)
              | ((unsigned long long)f32_to_bf16_rne(Pr[j].w) << 48);
            *(unsigned long long*)(smem + pwb[j]) = pk;
        }
        asm volatile("s_waitcnt lgkmcnt(0)" ::: "memory");
        __builtin_amdgcn_s_barrier();
        __builtin_amdgcn_sched_barrier(0);

        // 4 supersteps x 8 iter-barriers (matches consumer count)
        for (int s = 0; s < 4; ++s) {
#pragma unroll
            for (int it = 0; it < 8; ++it) {
                if (it == 0 && s < 3) {
                    // issue next superstep's 16 full-1KB-burst loads
#pragma unroll
                    for (int j = 0; j < 16; ++j)
                        Pr[j] = *(const f32x4*)(prow[j] + (size_t)(s + 1) * 256);
                }
                if (it == 4 && s < 3) {
                    // ~1400cy after issue: no stall. cvt + write ring (s+1)&1
                    asm volatile("s_waitcnt vmcnt(0)" ::: "memory");
#pragma unroll
                    for (int j = 0; j < 16; ++j) {
                        unsigned long long pk =
                            (unsigned long long)f32_to_bf16_rne(Pr[j].x)
                          | ((unsigned long long)f32_to_bf16_rne(Pr[j].y) << 16)
                          | ((unsigned long long)f32_to_bf16_rne(Pr[j].z) << 32)
                          | ((unsigned long long)f32_to_bf16_rne(Pr[j].w) << 48);
                        *(unsigned long long*)(smem + ((s + 1) & 1) * ARING + pwb[j]) = pk;
                    }
                    asm volatile("s_waitcnt lgkmcnt(0)" ::: "memory");
                }
                __builtin_amdgcn_s_barrier();
                __builtin_amdgcn_sched_barrier(0);
            }
        }

        // epilogue barrier (matches consumer wmax barrier)
        __builtin_amdgcn_s_barrier();
        __builtin_amdgcn_sched_barrier(0);
    }
}

// ---------------------------------------------------------------------------
// two-level threshold select (R12 verbatim)
// ---------------------------------------------------------------------------
__global__ void zero_sel(unsigned int* __restrict__ hc, unsigned int* __restrict__ hf,
                         int* __restrict__ cnt) {
    int i = blockIdx.x * 1024 + threadIdx.x;
    if (i < 8192) { hc[i] = 0; hf[i] = 0; }
    if (i == 0) cnt[0] = 0;
}

__global__ void hist_build(const float* __restrict__ scores, unsigned int* __restrict__ hist) {
    __shared__ unsigned int lh[8192];
    for (int i = threadIdx.x; i < 8192; i += 256) lh[i] = 0;
    __syncthreads();
    for (int i = blockIdx.x * 256 + threadIdx.x; i < MK; i += gridDim.x * 256)
        atomicAdd(&lh[xform(scores[i]) >> 19], 1u);
    __syncthreads();
    for (int i = threadIdx.x; i < 8192; i += 256) {
        unsigned int c = lh[i];
        if (c) atomicAdd(&hist[i], c);
    }
}

__launch_bounds__(1024)
__global__ void find_coarse(const unsigned int* __restrict__ hist, int* __restrict__ tb) {
    __shared__ unsigned int s0[1024], s1[1024];
    const int tid = threadIdx.x;
    unsigned int s = 0;
#pragma unroll
    for (int j = 0; j < 8; ++j) s += hist[tid * 8 + j];
    s0[tid] = s;
    __syncthreads();
    unsigned int* src = s0;
    unsigned int* dst = s1;
    for (int off = 1; off < 1024; off <<= 1) {
        unsigned int v = src[tid] + ((tid + off < 1024) ? src[tid + off] : 0u);
        __syncthreads();
        dst[tid] = v;
        __syncthreads();
        unsigned int* t = src; src = dst; dst = t;
    }
    unsigned int suf  = src[tid];
    unsigned int sufn = (tid < 1023) ? src[tid + 1] : 0u;
    if (suf >= 64u && sufn < 64u) {
        unsigned int acc = sufn, hb = 0;
        int b = tid * 8 + 7;
        for (;; --b) { hb = hist[b]; acc += hb; if (acc >= 64u) break; }
        tb[0] = b;
        tb[1] = (int)(acc - hb);   // count strictly above coarse bin b
    }
}

__global__ void hist_fine(const float* __restrict__ scores, const int* __restrict__ tb,
                          unsigned int* __restrict__ fh) {
    __shared__ unsigned int lh[8192];
    for (int i = threadIdx.x; i < 8192; i += 256) lh[i] = 0;
    __syncthreads();
    const unsigned int b = (unsigned int)tb[0];
    for (int i = blockIdx.x * 256 + threadIdx.x; i < MK; i += gridDim.x * 256) {
        unsigned int u = xform(scores[i]);
        if ((u >> 19) == b) atomicAdd(&lh[(u >> 6) & 8191u], 1u);
    }
    __syncthreads();
    for (int i = threadIdx.x; i < 8192; i += 256) {
        unsigned int c = lh[i];
        if (c) atomicAdd(&fh[i], c);
    }
}

__launch_bounds__(1024)
__global__ void find_fine(const unsigned int* __restrict__ fh, const int* __restrict__ tb,
                          float* __restrict__ vlo) {
    __shared__ unsigned int s0[1024], s1[1024];
    const int tid = threadIdx.x;
    const unsigned int init = (unsigned int)tb[1];
    unsigned int s = 0;
#pragma unroll
    for (int j = 0; j < 8; ++j) s += fh[tid * 8 + j];
    s0[tid] = s;
    __syncthreads();
    unsigned int* src = s0;
    unsigned int* dst = s1;
    for (int off = 1; off < 1024; off <<= 1) {
        unsigned int v = src[tid] + ((tid + off < 1024) ? src[tid + off] : 0u);
        __syncthreads();
        dst[tid] = v;
        __syncthreads();
        unsigned int* t = src; src = dst; dst = t;
    }
    unsigned int suf  = init + src[tid];
    unsigned int sufn = init + ((tid < 1023) ? src[tid + 1] : 0u);
    if (suf >= 64u && sufn < 64u) {
        unsigned int acc = sufn;
        int b = tid * 8 + 7;
        for (;; --b) { acc += fh[b]; if (acc >= 64u) break; }
        vlo[0] = unxform(((unsigned int)tb[0] << 19) | ((unsigned int)b << 6)) - 0.8f;
    }
}

__global__ void collect(const float* __restrict__ scores, const float* __restrict__ vlo,
                        int* __restrict__ cidx, int* __restrict__ cnt) {
    const float t = vlo[0];
    for (int i = blockIdx.x * 256 + threadIdx.x; i < MK; i += gridDim.x * 256) {
        if (scores[i] >= t) {
            int p = atomicAdd(cnt, 1);
            if (p < CAP) cidx[p] = i;
        }
    }
}

// ---------------------------------------------------------------------------
// exact f32 rescore: one block per candidate, max over 512 queries
// ---------------------------------------------------------------------------
__launch_bounds__(256)
__global__ void rescore(const float* __restrict__ q, const float* __restrict__ a,
                        const float* __restrict__ keys,
                        const int* __restrict__ cidx, const int* __restrict__ cnt,
                        float* __restrict__ resc) {
    __shared__ float wsm[1024];
    __shared__ float smax[4];
    const int b = blockIdx.x;
    if (b >= cnt[0]) return;
    const int m   = cidx[b];
    const int tid = threadIdx.x;

    for (int d = tid; d < 1024; d += 256) wsm[d] = a[d] * keys[(size_t)m * DD + d];
    __syncthreads();

    const int wid = tid >> 6, lane = tid & 63;
    float best = -__builtin_inff();
    for (int n = wid; n < NQ; n += 4) {
        const float* qr = q + (size_t)n * DD;
        float p = 0.f;
#pragma unroll
        for (int j = 0; j < 4; ++j) {
            float4 v  = *(const float4*)(qr + lane * 4 + 256 * j);
            float4 ww = *(const float4*)(&wsm[lane * 4 + 256 * j]);
            p += v.x * ww.x + v.y * ww.y + v.z * ww.z + v.w * ww.w;
        }
#pragma unroll
        for (int off = 1; off < 64; off <<= 1) p += __shfl_xor(p, off);
        best = fmaxf(best, p);
    }
    if (lane == 0) smax[wid] = best;
    __syncthreads();
    if (tid == 0)
        resc[b] = fmaxf(fmaxf(smax[0], smax[1]), fmaxf(smax[2], smax[3]));
}

// ---------------------------------------------------------------------------
// final: top-64 over candidates (exact vals, tie: idx asc), softmax, gather V
// ---------------------------------------------------------------------------
__launch_bounds__(256)
__global__ void final_select(const int* __restrict__ cidx, const float* __restrict__ resc,
                             const int* __restrict__ cnt, const float* __restrict__ values,
                             float* __restrict__ out) {
    __shared__ float selw[64];
    __shared__ int   seli[64];
    const int tid = threadIdx.x;
    int nc = cnt[0];
    if (nc > CAP) nc = CAP;

    if (tid < 64) {
        const int lane = tid;
        float lv[16]; int li[16];
#pragma unroll
        for (int j = 0; j < 16; ++j) {
            int slot = lane + 64 * j;
            bool ok = slot < nc;
            lv[j] = ok ? resc[slot] : -__builtin_inff();
            li[j] = ok ? cidx[slot] : 0x7fffffff;
        }
        for (int it = 0; it < 64; ++it) {
            float bv = -__builtin_inff();
            int bg = 0x7fffffff, bj = 0;
#pragma unroll
            for (int j = 0; j < 16; ++j)
                if (lv[j] > bv || (lv[j] == bv && li[j] < bg)) { bv = lv[j]; bg = li[j]; bj = j; }
            int bcode = (lane << 4) | bj;
#pragma unroll
            for (int off = 1; off < 64; off <<= 1) {
                float ov = __shfl_xor(bv, off);
                int   og = __shfl_xor(bg, off);
                int   oc = __shfl_xor(bcode, off);
                if (ov > bv || (ov == bv && og < bg)) { bv = ov; bg = og; bcode = oc; }
            }
            if ((bcode >> 4) == lane) {
                int wj = bcode & 15;
#pragma unroll
                for (int j = 0; j < 16; ++j) if (j == wj) lv[j] = -__builtin_inff();
            }
            if (lane == 0) { selw[it] = bv; seli[it] = bg; }
        }
    }
    __syncthreads();

    if (tid < 64) {
        float x = selw[tid];
        float mx = x;
#pragma unroll
        for (int off = 1; off < 64; off <<= 1) mx = fmaxf(mx, __shfl_xor(mx, off));
        float e = expf(x - mx);
        float s = e;
#pragma unroll
        for (int off = 1; off < 64; off <<= 1) s += __shfl_xor(s, off);
        selw[tid] = e / s;
        out[DD + tid] = (float)seli[tid];
    }
    __syncthreads();

    for (int d = tid; d < DD; d += 256) {
        float accv = 0.f;
        for (int i = 0; i < 64; ++i)
            accv += selw[i] * values[(size_t)seli[i] * DD + d];
        out[d] = accv;
    }
}

// ---------------------------------------------------------------------------
extern "C" void kernel_launch(void* const* d_in, const int* in_sizes, int n_in,
                              void* d_out, int out_size, void* d_ws, size_t ws_size,
                              hipStream_t stream) {
    (void)in_sizes; (void)n_in; (void)out_size; (void)ws_size;
    const float* queries = (const float*)d_in[0];
    const float* keys    = (const float*)d_in[1];
    const float* values  = (const float*)d_in[2];
    const float* affine  = (const float*)d_in[3];
    float* out = (float*)d_out;
    char*  ws  = (char*)d_ws;

    unsigned short* qstage = (unsigned short*)(ws + QSTAGE_OFF);
    float* scores = (float*)(ws + SCORES_OFF);
    int*   cidx   = (int*)(ws + CIDX_OFF);
    float* resc   = (float*)(ws + RESC_OFF);
    int*   cnt    = (int*)(ws + CNT_OFF);
    unsigned int* hc = (unsigned int*)(ws + HISTC_OFF);
    unsigned int* hf = (unsigned int*)(ws + HISTF_OFF);
    int*   tb     = (int*)(ws + TB_OFF);
    float* vlo    = (float*)(ws + VLO_OFF);

    hipFuncSetAttribute((const void*)scores_gemm,
                        hipFuncAttributeMaxDynamicSharedMemorySize, GEMM_LDS);

    prep_q<<<256, 256, 0, stream>>>(queries, affine, qstage);
    scores_gemm<<<MBLK, 512, GEMM_LDS, stream>>>(keys, qstage, scores);
    zero_sel<<<8, 1024, 0, stream>>>(hc, hf, cnt);
    hist_build<<<64, 256, 0, stream>>>(scores, hc);
    find_coarse<<<1, 1024, 0, stream>>>(hc, tb);
    hist_fine<<<64, 256, 0, stream>>>(scores, tb, hf);
    find_fine<<<1, 1024, 0, stream>>>(hf, tb, vlo);
    collect<<<200, 256, 0, stream>>>(scores, vlo, cidx, cnt);
    rescore<<<CAP, 256, 0, stream>>>(queries, affine, keys, cidx, cnt, resc);
    final_select<<<1, 256, 0, stream>>>(cidx, resc, cnt, values, out);
}